// Round 1
// baseline (439.799 us; speedup 1.0000x reference)
//
#include <hip/hip_runtime.h>

// SNN LIF scan: T=1024, B=32, N=2048.
// One thread per (b,n) sequence; sequential over t.
// d_out layout: spikes[T*B*N] ++ v_final[B*N] ++ i_final[B*N].

#define TT 1024
#define BN 65536          // B*N = 32*2048
#define UNROLL 16

__global__ __launch_bounds__(256) void snn_lif_kernel(
    const float* __restrict__ x,   // [T, B, N] flat
    float* __restrict__ out)       // spikes ++ v_f ++ i_f
{
    const int idx = blockIdx.x * 256 + threadIdx.x;   // 0..BN-1
    const float* __restrict__ xp = x + idx;
    float* __restrict__ sp = out + idx;

    float v = 0.0f;
    float i = 0.0f;

    const float c_mem = 0.1f;   // fp32(DT*TAU_MEM_INV)
    const float c_syn = 0.8f;   // fp32(1 - DT*TAU_SYN_INV)

    #pragma unroll 1
    for (int t0 = 0; t0 < TT; t0 += UNROLL) {
        // Batch-prefetch UNROLL timesteps (independent loads -> 16 outstanding
        // vmem ops per wave for HBM latency hiding at 1 wave/SIMD occupancy).
        float xv[UNROLL];
        #pragma unroll
        for (int k = 0; k < UNROLL; ++k) {
            xv[k] = xp[(size_t)(t0 + k) * BN];
        }
        // Sequential LIF updates. Use _rn intrinsics to forbid FMA
        // contraction: spike decisions are binary and must match the
        // reference's fp32 op-by-op rounding exactly.
        #pragma unroll
        for (int k = 0; k < UNROLL; ++k) {
            // v_dec = v + 0.1 * ((0 - v) + i)
            float dv    = __fmul_rn(c_mem, __fadd_rn(__fsub_rn(0.0f, v), i));
            float v_dec = __fadd_rn(v, dv);
            // i_dec = i * 0.8
            float i_dec = __fmul_rn(i, c_syn);
            // z = (v_dec - 1.0 > 0); reset v to 0 on spike
            bool fired = (v_dec > 1.0f);
            float z = fired ? 1.0f : 0.0f;
            v = fired ? 0.0f : v_dec;
            // i_new = i_dec + x_t
            i = __fadd_rn(i_dec, xv[k]);
            sp[(size_t)(t0 + k) * BN] = z;
        }
    }

    out[(size_t)TT * BN + idx]      = v;
    out[(size_t)TT * BN + BN + idx] = i;
}

extern "C" void kernel_launch(void* const* d_in, const int* in_sizes, int n_in,
                              void* d_out, int out_size, void* d_ws, size_t ws_size,
                              hipStream_t stream) {
    const float* x = (const float*)d_in[0];
    float* out = (float*)d_out;
    // BN threads total, 256/block -> 256 blocks (one per CU).
    snn_lif_kernel<<<BN / 256, 256, 0, stream>>>(x, out);
}

// Round 3
// 434.666 us; speedup vs baseline: 1.0118x; 1.0118x over previous
//
#include <hip/hip_runtime.h>

// SNN LIF scan: T=1024, B=32, N=2048. EXACT sequential-in-T (R2 showed spikes
// are binary -> trajectory must be bit-exact -> no T-parallelization).
// One thread per (b,n); software-pipelined ping-pong load batches so HBM
// latency overlaps compute of the previous batch. Non-temporal spike stores
// keep the harness-restore-warmed x resident in L3 (R1: FETCH was only half
// the input thanks to L3).
// d_out layout: spikes[T*B*N] ++ v_final[B*N] ++ i_final[B*N].

#define TT 1024
#define BN 65536          // B*N = 32*2048
#define U  16             // batch size per pipeline phase

__global__ __launch_bounds__(256) void snn_lif_kernel(
    const float* __restrict__ x,   // [T, B, N] flat
    float* __restrict__ out)       // spikes ++ v_f ++ i_f
{
    const int idx = blockIdx.x * 256 + threadIdx.x;   // 0..BN-1
    const float* __restrict__ xp = x + idx;
    float* __restrict__ sp = out + idx;

    float v = 0.0f;
    float i = 0.0f;

    const float c_mem = 0.1f;   // fp32(DT*TAU_MEM_INV)
    const float c_syn = 0.8f;   // fp32(1 - DT*TAU_SYN_INV)

    float xa[U], xb[U];

    // Prologue: first batch in flight.
    #pragma unroll
    for (int k = 0; k < U; ++k)
        xa[k] = xp[(size_t)k * BN];

    #pragma unroll 1
    for (int t0 = 0; t0 < TT; t0 += 2 * U) {
        // Issue batch B (t0+U .. t0+2U-1) before consuming batch A:
        // loads stay in flight during A's dependent-chain compute.
        #pragma unroll
        for (int k = 0; k < U; ++k)
            xb[k] = xp[(size_t)(t0 + U + k) * BN];

        #pragma unroll
        for (int k = 0; k < U; ++k) {
            // Exact ref op sequence; _rn intrinsics forbid FMA contraction
            // (spike decisions are binary -- must match fp32 ref bit-exactly).
            float dv    = __fmul_rn(c_mem, __fadd_rn(__fsub_rn(0.0f, v), i));
            float v_dec = __fadd_rn(v, dv);
            float i_dec = __fmul_rn(i, c_syn);
            bool fired  = (v_dec > 1.0f);
            v = fired ? 0.0f : v_dec;
            i = __fadd_rn(i_dec, xa[k]);
            __builtin_nontemporal_store(fired ? 1.0f : 0.0f,
                                        &sp[(size_t)(t0 + k) * BN]);
        }

        // Refill batch A for the next outer iteration (uniform branch).
        if (t0 + 2 * U < TT) {
            #pragma unroll
            for (int k = 0; k < U; ++k)
                xa[k] = xp[(size_t)(t0 + 2 * U + k) * BN];
        }

        #pragma unroll
        for (int k = 0; k < U; ++k) {
            float dv    = __fmul_rn(c_mem, __fadd_rn(__fsub_rn(0.0f, v), i));
            float v_dec = __fadd_rn(v, dv);
            float i_dec = __fmul_rn(i, c_syn);
            bool fired  = (v_dec > 1.0f);
            v = fired ? 0.0f : v_dec;
            i = __fadd_rn(i_dec, xb[k]);
            __builtin_nontemporal_store(fired ? 1.0f : 0.0f,
                                        &sp[(size_t)(t0 + U + k) * BN]);
        }
    }

    out[(size_t)TT * BN + idx]      = v;
    out[(size_t)TT * BN + BN + idx] = i;
}

extern "C" void kernel_launch(void* const* d_in, const int* in_sizes, int n_in,
                              void* d_out, int out_size, void* d_ws, size_t ws_size,
                              hipStream_t stream) {
    const float* x = (const float*)d_in[0];
    float* out = (float*)d_out;
    snn_lif_kernel<<<BN / 256, 256, 0, stream>>>(x, out);
}